// Round 1
// baseline (903.240 us; speedup 1.0000x reference)
//
#include <hip/hip_runtime.h>
#include <math.h>

#define B_   32
#define T_   60
#define D_   300
#define HID  100
#define G4   400   // 4*HID gates
#define L_   20

// ---- workspace layout (in floats) ----
// xp   : 4 * 1920 * 400 = 3,072,000   (reused for ctx then agg input GEMM outputs)
// hsc  : 4 * 32*60*100  =   768,000   (ctx hidden states, scans: 0=p,f 1=p,b 2=h,f 3=h,b)
// hsa  : 4 * 32*60*100  =   768,000   (agg hidden states)
// mv   : 2 * 32*60*160  =   614,400   (mv_p then mv_h)
// av   : 2*4*32*100     =    25,600   (attn vectors: per dir: mean_h0,max_h0,mean_p0,max_p0)
#define XP_OFF   0u
#define HSC_OFF  3072000u
#define HSA_OFF  3840000u
#define MV_OFF   4608000u
#define AV_OFF   5222400u

// ---------------- GEMM with optional row-gather + bias ----------------
// C[m][n] = bias[n] + sum_k A[row(m)][k] * W[n*K+k],  M fixed 1920 (divisible by 64)
__global__ __launch_bounds__(256) void gemm_bias(
    const float* __restrict__ A, const int* __restrict__ idx,
    const float* __restrict__ W, const float* __restrict__ bias,
    float* __restrict__ C, int N, int K)
{
    __shared__ float As[16][65];
    __shared__ float Bs[16][65];
    const int tid = threadIdx.x;
    const int m0 = blockIdx.y * 64, n0 = blockIdx.x * 64;
    const int tm = (tid >> 4) << 2;
    const int tn = (tid & 15) << 2;
    float acc[4][4] = {};
    for (int k0 = 0; k0 < K; k0 += 16) {
        for (int e = tid; e < 64 * 16; e += 256) {
            const int mm = e >> 4, kk = e & 15;
            const int m = m0 + mm, k = k0 + kk;
            const int row = idx ? idx[m] : m;
            As[kk][mm] = (k < K) ? A[(size_t)row * K + k] : 0.f;
        }
        for (int e = tid; e < 64 * 16; e += 256) {
            const int nn = e >> 4, kk = e & 15;
            const int n = n0 + nn, k = k0 + kk;
            Bs[kk][nn] = (n < N && k < K) ? W[(size_t)n * K + k] : 0.f;
        }
        __syncthreads();
        #pragma unroll
        for (int kk = 0; kk < 16; ++kk) {
            float a[4], b[4];
            #pragma unroll
            for (int i = 0; i < 4; i++) a[i] = As[kk][tm + i];
            #pragma unroll
            for (int j = 0; j < 4; j++) b[j] = Bs[kk][tn + j];
            #pragma unroll
            for (int i = 0; i < 4; i++)
                #pragma unroll
                for (int j = 0; j < 4; j++) acc[i][j] = fmaf(a[i], b[j], acc[i][j]);
        }
        __syncthreads();
    }
    #pragma unroll
    for (int i = 0; i < 4; i++)
        #pragma unroll
        for (int j = 0; j < 4; j++) {
            const int m = m0 + tm + i, n = n0 + tn + j;
            if (n < N) C[(size_t)m * N + n] = acc[i][j] + bias[n];
        }
}

// ---------------- LSTM scan: 4 independent scans, 2 batches per block ----------------
// xp: [4][B][T][400] precomputed x@Wih^T + bih; hs: [4][B][T][100] outputs,
// stored at re-reversed time position for backward scans (dir = s&1).
__global__ __launch_bounds__(512) void lstm_scan(
    const float* __restrict__ xp,
    const float* __restrict__ Whh_f, const float* __restrict__ Whh_b,
    const float* __restrict__ bhh_f, const float* __restrict__ bhh_b,
    float* __restrict__ hs)
{
    const int blk = blockIdx.x;
    const int s = blk >> 4, bp = blk & 15;
    const int dir = s & 1;
    const float* __restrict__ Whh = dir ? Whh_b : Whh_f;
    const float* __restrict__ bhh = dir ? bhh_b : bhh_f;
    const int tid = threadIdx.x;

    __shared__ __align__(16) float h_lds[2][HID];
    __shared__ float c_lds[2][HID];
    __shared__ float gact[2][G4];

    if (tid < 2 * HID) {
        h_lds[tid / HID][tid % HID] = 0.f;
        c_lds[tid / HID][tid % HID] = 0.f;
    }

    float wreg[HID];
    float bias = 0.f;
    if (tid < G4) {
        bias = bhh[tid];
        #pragma unroll
        for (int k = 0; k < HID; ++k) wreg[k] = Whh[tid * HID + k];
    }
    const float* __restrict__ xp0 = xp + ((size_t)s * B_ + bp * 2) * T_ * G4;
    float* __restrict__ hs0 = hs + ((size_t)s * B_ + bp * 2) * T_ * HID;
    __syncthreads();

    for (int st = 0; st < T_; ++st) {
        const int t = dir ? (T_ - 1 - st) : st;
        if (tid < G4) {
            float acc0 = bias + xp0[(size_t)t * G4 + tid];
            float acc1 = bias + xp0[(size_t)(T_ + t) * G4 + tid];
            #pragma unroll
            for (int k = 0; k < HID; k += 4) {
                const float4 h0 = *reinterpret_cast<const float4*>(&h_lds[0][k]);
                const float4 h1 = *reinterpret_cast<const float4*>(&h_lds[1][k]);
                acc0 = fmaf(h0.x, wreg[k], acc0);
                acc0 = fmaf(h0.y, wreg[k + 1], acc0);
                acc0 = fmaf(h0.z, wreg[k + 2], acc0);
                acc0 = fmaf(h0.w, wreg[k + 3], acc0);
                acc1 = fmaf(h1.x, wreg[k], acc1);
                acc1 = fmaf(h1.y, wreg[k + 1], acc1);
                acc1 = fmaf(h1.z, wreg[k + 2], acc1);
                acc1 = fmaf(h1.w, wreg[k + 3], acc1);
            }
            const int chunk = tid / HID;  // 0:i 1:f 2:g 3:o
            float a0, a1;
            if (chunk == 2) { a0 = tanhf(acc0); a1 = tanhf(acc1); }
            else { a0 = 1.f / (1.f + expf(-acc0)); a1 = 1.f / (1.f + expf(-acc1)); }
            gact[0][tid] = a0;
            gact[1][tid] = a1;
        }
        __syncthreads();
        if (tid < 2 * HID) {
            const int b = tid / HID, j = tid % HID;
            const float iv = gact[b][j], fv = gact[b][HID + j];
            const float gv = gact[b][2 * HID + j], ov = gact[b][3 * HID + j];
            const float c = fv * c_lds[b][j] + iv * gv;
            const float hv = ov * tanhf(c);
            c_lds[b][j] = c;
            h_lds[b][j] = hv;
            hs0[(size_t)(b * T_ + t) * HID + j] = hv;
        }
        __syncthreads();
    }
}

// ---------------- attention row0/col0 + mean/max vectors ----------------
// av[(d*4+vec)][B][HID], vec: 0=mean_h0 1=max_h0 2=mean_p0 3=max_p0
__global__ __launch_bounds__(128) void attn_kernel(
    const float* __restrict__ hs_ctx, float* __restrict__ av)
{
    const int d = blockIdx.x >> 5;
    const int b = blockIdx.x & 31;
    const float* __restrict__ cp = hs_ctx + ((size_t)(0 + d) * B_ + b) * T_ * HID;
    const float* __restrict__ ch = hs_ctx + ((size_t)(2 + d) * B_ + b) * T_ * HID;
    const int tid = threadIdx.x;
    __shared__ float cp0[HID], ch0[HID];
    __shared__ float arow[T_], acol[T_];
    __shared__ float nrm[2], asum[2];
    if (tid < HID) { cp0[tid] = cp[tid]; ch0[tid] = ch[tid]; }
    __syncthreads();
    if (tid < 2) {
        const float* v = tid ? ch0 : cp0;
        float sum = 0.f;
        for (int h = 0; h < HID; h++) sum += v[h] * v[h];
        nrm[tid] = sqrtf(sum);
    }
    __syncthreads();
    if (tid < T_) {
        const float* r = ch + (size_t)tid * HID;
        float dot = 0.f, n2 = 0.f;
        for (int h = 0; h < HID; h++) { const float x = r[h]; dot += cp0[h] * x; n2 += x * x; }
        arow[tid] = dot / (nrm[0] * sqrtf(n2));
    } else if (tid >= 64 && tid < 64 + T_) {
        const int i = tid - 64;
        const float* r = cp + (size_t)i * HID;
        float dot = 0.f, n2 = 0.f;
        for (int h = 0; h < HID; h++) { const float x = r[h]; dot += x * ch0[h]; n2 += x * x; }
        acol[i] = dot / (sqrtf(n2) * nrm[1]);
    }
    __syncthreads();
    if (tid < 2) {
        const float* a = tid ? acol : arow;
        float sum = 0.f;
        for (int j = 0; j < T_; j++) sum += a[j];
        asum[tid] = sum;
    }
    __syncthreads();
    if (tid < HID) {
        float m = 0.f, mx = -INFINITY;
        for (int j = 0; j < T_; j++) {
            const float x = ch[(size_t)j * HID + tid] * arow[j];
            m += x; mx = fmaxf(mx, x);
        }
        av[((size_t)(d * 4 + 0) * B_ + b) * HID + tid] = m / (asum[0] + 1e-10f);
        av[((size_t)(d * 4 + 1) * B_ + b) * HID + tid] = mx;
        float m2 = 0.f, mx2 = -INFINITY;
        for (int i = 0; i < T_; i++) {
            const float x = cp[(size_t)i * HID + tid] * acol[i];
            m2 += x; mx2 = fmaxf(mx2, x);
        }
        av[((size_t)(d * 4 + 2) * B_ + b) * HID + tid] = m2 / (asum[1] + 1e-10f);
        av[((size_t)(d * 4 + 3) * B_ + b) * HID + tid] = mx2;
    }
}

// ---------------- multi-perspective single (v1 vs broadcast u) ----------------
struct MPCfg {
    const float* v1;   // (B,T,HID)
    const float* u;    // u[b][h] = u[b*ustride + h]
    int ustride;
    const float* w;    // (HID, L)
    float* outp;       // (B,T,160)
    int choff;
};
struct MPCfgs { MPCfg c[12]; };

__global__ __launch_bounds__(256) void mp_single_kernel(MPCfgs cfgs)
{
    const int ci = blockIdx.x >> 5;
    const int b = blockIdx.x & 31;
    const MPCfg cfg = cfgs.c[ci];
    const int tid = threadIdx.x;
    __shared__ float w2[HID][L_];
    __shared__ float uw[HID][L_];
    __shared__ float u_l[HID];
    __shared__ float nul[L_];
    if (tid < HID) u_l[tid] = cfg.u[(size_t)b * cfg.ustride + tid];
    for (int e = tid; e < HID * L_; e += 256) {
        const float wv = cfg.w[e];
        w2[e / L_][e % L_] = wv * wv;
    }
    __syncthreads();
    for (int e = tid; e < HID * L_; e += 256) uw[e / L_][e % L_] = w2[e / L_][e % L_] * u_l[e / L_];
    if (tid < L_) {
        float sum = 0.f;
        for (int h = 0; h < HID; h++) sum += u_l[h] * u_l[h] * w2[h][tid];
        nul[tid] = sqrtf(sum);
    }
    __syncthreads();
    const float* __restrict__ v1b = cfg.v1 + (size_t)b * T_ * HID;
    for (int p = tid; p < T_ * L_; p += 256) {
        const int i = p / L_, l = p % L_;
        const float* __restrict__ v = v1b + (size_t)i * HID;
        float num = 0.f, den = 0.f;
        for (int h = 0; h < HID; h++) {
            const float x = v[h];
            num = fmaf(x, uw[h][l], num);
            den = fmaf(x * x, w2[h][l], den);
        }
        cfg.outp[((size_t)b * T_ + i) * 160 + cfg.choff + l] = num / (sqrtf(den) * nul[l]);
    }
}

// ---------------- pairwise multi-perspective max ----------------
// grid: d(2) x b(32) x l(20); writes mv_p[...][d*80+20+l] (max over j) and mv_h (max over i)
__global__ __launch_bounds__(256) void mp_pair_kernel(
    const float* __restrict__ hs_ctx, const float* __restrict__ w3,
    const float* __restrict__ w4, float* __restrict__ mv_p, float* __restrict__ mv_h)
{
    const int x = blockIdx.x;
    const int l = x % L_;
    const int b = (x / L_) & 31;
    const int d = x / (L_ * B_);
    const float* __restrict__ cp = hs_ctx + ((size_t)(0 + d) * B_ + b) * T_ * HID;
    const float* __restrict__ ch = hs_ctx + ((size_t)(2 + d) * B_ + b) * T_ * HID;
    const float* __restrict__ w = d ? w4 : w3;
    const int tid = threadIdx.x;
    __shared__ float U[T_][HID];
    __shared__ float V[T_][HID];
    __shared__ float aw[HID];
    __shared__ float n1[T_], n2[T_];
    __shared__ float pmi[T_][15];
    __shared__ float pmj[15][T_];
    if (tid < HID) aw[tid] = fabsf(w[tid * L_ + l]);
    __syncthreads();
    for (int e = tid; e < T_ * HID; e += 256) {
        const int i = e / HID, h = e % HID;
        U[i][h] = cp[e] * aw[h];
        V[i][h] = ch[e] * aw[h];
    }
    __syncthreads();
    if (tid < T_) {
        float sum = 0.f;
        for (int h = 0; h < HID; h++) { const float v = U[tid][h]; sum += v * v; }
        n1[tid] = sqrtf(sum);
    } else if (tid >= 128 && tid < 128 + T_) {
        const int j = tid - 128;
        float sum = 0.f;
        for (int h = 0; h < HID; h++) { const float v = V[j][h]; sum += v * v; }
        n2[j] = sqrtf(sum);
    }
    __syncthreads();
    if (tid < 225) {
        const int ti = tid / 15, tj = tid % 15;
        const int i0 = ti * 4, j0 = tj * 4;
        float acc[4][4] = {};
        for (int h = 0; h < HID; ++h) {
            float uu[4], vv[4];
            #pragma unroll
            for (int r = 0; r < 4; r++) uu[r] = U[i0 + r][h];
            #pragma unroll
            for (int s2 = 0; s2 < 4; s2++) vv[s2] = V[j0 + s2][h];
            #pragma unroll
            for (int r = 0; r < 4; r++)
                #pragma unroll
                for (int s2 = 0; s2 < 4; s2++) acc[r][s2] = fmaf(uu[r], vv[s2], acc[r][s2]);
        }
        float rmax[4] = {-INFINITY, -INFINITY, -INFINITY, -INFINITY};
        float cmax[4] = {-INFINITY, -INFINITY, -INFINITY, -INFINITY};
        #pragma unroll
        for (int r = 0; r < 4; r++)
            #pragma unroll
            for (int s2 = 0; s2 < 4; s2++) {
                const float val = acc[r][s2] / (n1[i0 + r] * n2[j0 + s2]);
                rmax[r] = fmaxf(rmax[r], val);
                cmax[s2] = fmaxf(cmax[s2], val);
            }
        #pragma unroll
        for (int r = 0; r < 4; r++) pmi[i0 + r][tj] = rmax[r];
        #pragma unroll
        for (int s2 = 0; s2 < 4; s2++) pmj[ti][j0 + s2] = cmax[s2];
    }
    __syncthreads();
    if (tid < T_) {
        float mx = -INFINITY;
        for (int q = 0; q < 15; q++) mx = fmaxf(mx, pmi[tid][q]);
        mv_p[((size_t)b * T_ + tid) * 160 + d * 80 + 20 + l] = mx;
    } else if (tid >= 128 && tid < 128 + T_) {
        const int j = tid - 128;
        float mx = -INFINITY;
        for (int q = 0; q < 15; q++) mx = fmaxf(mx, pmj[q][j]);
        mv_h[((size_t)b * T_ + j) * 160 + d * 80 + 20 + l] = mx;
    }
}

// ---------------- final FC ----------------
__global__ __launch_bounds__(256) void fc_final(
    const float* __restrict__ hs_agg, const float* __restrict__ fc1W,
    const float* __restrict__ fc1b, const float* __restrict__ fc2W,
    const float* __restrict__ fc2b, float* __restrict__ out)
{
    const int b = blockIdx.x;
    const int tid = threadIdx.x;
    __shared__ float x[400];
    __shared__ float y[200];
    if (tid < HID) {
        x[tid]           = hs_agg[((size_t)(0 * B_ + b) * T_ + 59) * HID + tid];
        x[HID + tid]     = hs_agg[((size_t)(1 * B_ + b) * T_ + 0) * HID + tid];
        x[2 * HID + tid] = hs_agg[((size_t)(2 * B_ + b) * T_ + 59) * HID + tid];
        x[3 * HID + tid] = hs_agg[((size_t)(3 * B_ + b) * T_ + 0) * HID + tid];
    }
    __syncthreads();
    if (tid < 200) {
        float s = fc1b[tid];
        const float* __restrict__ wr = fc1W + (size_t)tid * 400;
        for (int k = 0; k < 400; k++) s = fmaf(x[k], wr[k], s);
        y[tid] = tanhf(s);
    }
    __syncthreads();
    if (tid < 3) {
        float s = fc2b[tid];
        const float* __restrict__ wr = fc2W + (size_t)tid * 200;
        for (int k = 0; k < 200; k++) s = fmaf(y[k], wr[k], s);
        out[b * 3 + tid] = s;
    }
}

extern "C" void kernel_launch(void* const* d_in, const int* in_sizes, int n_in,
                              void* d_out, int out_size, void* d_ws, size_t ws_size,
                              hipStream_t stream) {
    const int* p_idx = (const int*)d_in[0];
    const int* h_idx = (const int*)d_in[1];
    const float* emb = (const float*)d_in[2];
    const float* ctx_Wih_f = (const float*)d_in[3];
    const float* ctx_Whh_f = (const float*)d_in[4];
    const float* ctx_bih_f = (const float*)d_in[5];
    const float* ctx_bhh_f = (const float*)d_in[6];
    const float* ctx_Wih_b = (const float*)d_in[7];
    const float* ctx_Whh_b = (const float*)d_in[8];
    const float* ctx_bih_b = (const float*)d_in[9];
    const float* ctx_bhh_b = (const float*)d_in[10];
    const float* agg_Wih_f = (const float*)d_in[11];
    const float* agg_Whh_f = (const float*)d_in[12];
    const float* agg_bih_f = (const float*)d_in[13];
    const float* agg_bhh_f = (const float*)d_in[14];
    const float* agg_Wih_b = (const float*)d_in[15];
    const float* agg_Whh_b = (const float*)d_in[16];
    const float* agg_bih_b = (const float*)d_in[17];
    const float* agg_bhh_b = (const float*)d_in[18];
    const float* w1 = (const float*)d_in[19];
    const float* w2 = (const float*)d_in[20];
    const float* w3 = (const float*)d_in[21];
    const float* w4 = (const float*)d_in[22];
    const float* w5 = (const float*)d_in[23];
    const float* w6 = (const float*)d_in[24];
    const float* w7 = (const float*)d_in[25];
    const float* w8 = (const float*)d_in[26];
    const float* fc1W = (const float*)d_in[27];
    const float* fc1b = (const float*)d_in[28];
    const float* fc2W = (const float*)d_in[29];
    const float* fc2b = (const float*)d_in[30];

    float* ws = (float*)d_ws;
    float* xp = ws + XP_OFF;
    float* hsc = ws + HSC_OFF;
    float* hsa = ws + HSA_OFF;
    float* mvp = ws + MV_OFF;
    float* mvh = mvp + (size_t)B_ * T_ * 160;
    float* av = ws + AV_OFF;

    const dim3 ggrid(7, 30);  // N=400 -> 7 tiles of 64, M=1920 -> 30

    // ctx input GEMMs (emb gather fused), K=300
    gemm_bias<<<ggrid, 256, 0, stream>>>(emb, p_idx, ctx_Wih_f, ctx_bih_f, xp + 0 * 768000, 400, 300);
    gemm_bias<<<ggrid, 256, 0, stream>>>(emb, p_idx, ctx_Wih_b, ctx_bih_b, xp + 1 * 768000, 400, 300);
    gemm_bias<<<ggrid, 256, 0, stream>>>(emb, h_idx, ctx_Wih_f, ctx_bih_f, xp + 2 * 768000, 400, 300);
    gemm_bias<<<ggrid, 256, 0, stream>>>(emb, h_idx, ctx_Wih_b, ctx_bih_b, xp + 3 * 768000, 400, 300);

    lstm_scan<<<64, 512, 0, stream>>>(xp, ctx_Whh_f, ctx_Whh_b, ctx_bhh_f, ctx_bhh_b, hsc);

    attn_kernel<<<64, 128, 0, stream>>>(hsc, av);

    // mp_single configs: per dir d: full / am / amax for both mv_p and mv_h
    MPCfgs cfgs;
    for (int d = 0; d < 2; d++) {
        const float* cp_d = hsc + (size_t)(0 + d) * B_ * T_ * HID;
        const float* ch_d = hsc + (size_t)(2 + d) * B_ * T_ * HID;
        const int last = d ? 0 : (T_ - 1);
        const float* wfull = d ? w2 : w1;
        const float* wam = d ? w6 : w5;
        const float* wamax = d ? w8 : w7;
        float* avp0 = av + (size_t)(d * 4 + 0) * B_ * HID;  // mean_h0
        float* avp1 = av + (size_t)(d * 4 + 1) * B_ * HID;  // max_h0
        float* avp2 = av + (size_t)(d * 4 + 2) * B_ * HID;  // mean_p0
        float* avp3 = av + (size_t)(d * 4 + 3) * B_ * HID;  // max_p0
        cfgs.c[d * 6 + 0] = {cp_d, ch_d + last * HID, T_ * HID, wfull, mvp, d * 80 + 0};
        cfgs.c[d * 6 + 1] = {cp_d, avp0, HID, wam, mvp, d * 80 + 40};
        cfgs.c[d * 6 + 2] = {cp_d, avp1, HID, wamax, mvp, d * 80 + 60};
        cfgs.c[d * 6 + 3] = {ch_d, cp_d + last * HID, T_ * HID, wfull, mvh, d * 80 + 0};
        cfgs.c[d * 6 + 4] = {ch_d, avp2, HID, wam, mvh, d * 80 + 40};
        cfgs.c[d * 6 + 5] = {ch_d, avp3, HID, wamax, mvh, d * 80 + 60};
    }
    mp_single_kernel<<<384, 256, 0, stream>>>(cfgs);
    mp_pair_kernel<<<1280, 256, 0, stream>>>(hsc, w3, w4, mvp, mvh);

    // agg input GEMMs, K=160 (xp reused)
    gemm_bias<<<ggrid, 256, 0, stream>>>(mvp, nullptr, agg_Wih_f, agg_bih_f, xp + 0 * 768000, 400, 160);
    gemm_bias<<<ggrid, 256, 0, stream>>>(mvp, nullptr, agg_Wih_b, agg_bih_b, xp + 1 * 768000, 400, 160);
    gemm_bias<<<ggrid, 256, 0, stream>>>(mvh, nullptr, agg_Wih_f, agg_bih_f, xp + 2 * 768000, 400, 160);
    gemm_bias<<<ggrid, 256, 0, stream>>>(mvh, nullptr, agg_Wih_b, agg_bih_b, xp + 3 * 768000, 400, 160);

    lstm_scan<<<64, 512, 0, stream>>>(xp, agg_Whh_f, agg_Whh_b, agg_bhh_f, agg_bhh_b, hsa);

    fc_final<<<32, 256, 0, stream>>>(hsa, fc1W, fc1b, fc2W, fc2b, (float*)d_out);
}

// Round 3
// 411.121 us; speedup vs baseline: 2.1970x; 2.1970x over previous
//
#include <hip/hip_runtime.h>
#include <math.h>

#define B_   32
#define T_   60
#define D_   300
#define HID  100
#define G4   400   // 4*HID gates
#define L_   20

// ---- workspace layout (in floats) ----
#define XP_OFF   0u
#define HSC_OFF  3072000u
#define HSA_OFF  3840000u
#define MV_OFF   4608000u
#define AV_OFF   5222400u

// ---------------- fused dual GEMM with optional row-gather + bias ----------------
// Computes C[s][m][n] for s = 2*(src==A1) + (weights==Wb);
// M = 2*1920 rows (A0 rows then A1 rows), N = 2*400 cols (Wf then Wb), layout [4][1920][400].
__global__ __launch_bounds__(256) void gemm_dual(
    const float* __restrict__ A0, const float* __restrict__ A1,
    const int* __restrict__ idx0, const int* __restrict__ idx1,
    const float* __restrict__ Wf, const float* __restrict__ Wb,
    const float* __restrict__ bf, const float* __restrict__ bb,
    float* __restrict__ C, int K)
{
    __shared__ float As[16][68];
    __shared__ float Bs[16][68];
    const int tid = threadIdx.x;
    const int m0 = blockIdx.y * 64;   // 0..3776
    const int n0 = blockIdx.x * 64;   // 0..768
    const bool is_h = (m0 >= 1920);
    const float* __restrict__ Abase = is_h ? A1 : A0;
    const int* __restrict__ idx = is_h ? idx1 : idx0;
    const int mloc0 = m0 - (is_h ? 1920 : 0);

    const int r = tid >> 2;        // 0..63
    const int q = tid & 3;         // 0..3

    const int arow = mloc0 + r;
    const int srow = idx ? idx[arow] : arow;
    const float* __restrict__ Arow = Abase + (size_t)srow * K;
    const int n_my = n0 + r;
    const float* __restrict__ Wrow = (n_my < 400) ? (Wf + (size_t)n_my * K)
                      : ((n_my < 800) ? (Wb + (size_t)(n_my - 400) * K) : nullptr);

    const int tm = (tid >> 4) << 2;
    const int tn = (tid & 15) << 2;
    float acc[4][4] = {};
    for (int k0 = 0; k0 < K; k0 += 16) {
        const int k = k0 + q * 4;
        float4 av4 = make_float4(0.f, 0.f, 0.f, 0.f);
        float4 bv4 = make_float4(0.f, 0.f, 0.f, 0.f);
        if (k < K) av4 = *reinterpret_cast<const float4*>(Arow + k);
        if (Wrow != nullptr && k < K) bv4 = *reinterpret_cast<const float4*>(Wrow + k);
        __syncthreads();
        As[q * 4 + 0][r] = av4.x; As[q * 4 + 1][r] = av4.y;
        As[q * 4 + 2][r] = av4.z; As[q * 4 + 3][r] = av4.w;
        Bs[q * 4 + 0][r] = bv4.x; Bs[q * 4 + 1][r] = bv4.y;
        Bs[q * 4 + 2][r] = bv4.z; Bs[q * 4 + 3][r] = bv4.w;
        __syncthreads();
        #pragma unroll
        for (int kk = 0; kk < 16; ++kk) {
            const float4 a4 = *reinterpret_cast<const float4*>(&As[kk][tm]);
            const float4 b4 = *reinterpret_cast<const float4*>(&Bs[kk][tn]);
            const float a[4] = {a4.x, a4.y, a4.z, a4.w};
            const float b[4] = {b4.x, b4.y, b4.z, b4.w};
            #pragma unroll
            for (int i = 0; i < 4; i++)
                #pragma unroll
                for (int j = 0; j < 4; j++) acc[i][j] = fmaf(a[i], b[j], acc[i][j]);
        }
    }
    #pragma unroll
    for (int i = 0; i < 4; i++)
        #pragma unroll
        for (int j = 0; j < 4; j++) {
            const int n = n0 + tn + j;
            if (n < 800) {
                const int m = m0 + tm + i;
                const int s = (m >= 1920 ? 2 : 0) + (n >= 400 ? 1 : 0);
                const int ml = m - (m >= 1920 ? 1920 : 0);
                const int nl = n - (n >= 400 ? 400 : 0);
                const float bias = (n >= 400) ? bb[nl] : bf[nl];
                C[((size_t)s * 1920 + ml) * 400 + nl] = acc[i][j] + bias;
            }
        }
}

// ---------------- LSTM scan: 1 (scan,batch) per block, 128 blocks ----------------
// xp: [4][B][T][400] precomputed x@Wih^T + bih; hs: [4][B][T][100],
// backward scans (dir = s&1) stored at re-reversed time position.
__global__ __launch_bounds__(512, 1) void lstm_scan(
    const float* __restrict__ xp,
    const float* __restrict__ Whh_f, const float* __restrict__ Whh_b,
    const float* __restrict__ bhh_f, const float* __restrict__ bhh_b,
    float* __restrict__ hs)
{
    const int blk = blockIdx.x;
    const int s = blk >> 5, b = blk & 31;
    const int dir = s & 1;
    const float* __restrict__ Whh = dir ? Whh_b : Whh_f;
    const float* __restrict__ bhh = dir ? bhh_b : bhh_f;
    const int tid = threadIdx.x;

    __shared__ __align__(16) float h_lds[HID];
    __shared__ float gact[G4];

    float wreg[HID];
    float bias = 0.f;
    if (tid < G4) {
        bias = bhh[tid];
        #pragma unroll
        for (int k = 0; k < HID; ++k) wreg[k] = Whh[tid * HID + k];
    }
    if (tid < HID) h_lds[tid] = 0.f;
    float c_reg = 0.f;

    const float* __restrict__ xp0 = xp + ((size_t)s * B_ + b) * T_ * G4;
    float* __restrict__ hs0 = hs + ((size_t)s * B_ + b) * T_ * HID;

    int t = dir ? (T_ - 1) : 0;
    const int tstep = dir ? -1 : 1;
    float xr = (tid < G4) ? xp0[(size_t)t * G4 + tid] : 0.f;
    __syncthreads();

    for (int st = 0; st < T_; ++st) {
        const int tcur = t;
        if (tid < G4) {
            float a0 = bias + xr, a1 = 0.f, a2 = 0.f, a3 = 0.f;
            #pragma unroll
            for (int k = 0; k < HID; k += 4) {
                const float4 h4 = *reinterpret_cast<const float4*>(&h_lds[k]);
                a0 = fmaf(h4.x, wreg[k + 0], a0);
                a1 = fmaf(h4.y, wreg[k + 1], a1);
                a2 = fmaf(h4.z, wreg[k + 2], a2);
                a3 = fmaf(h4.w, wreg[k + 3], a3);
            }
            // prefetch next timestep's xp while activation + phase B run
            if (st + 1 < T_) xr = xp0[(size_t)(t + tstep) * G4 + tid];
            const float acc = (a0 + a1) + (a2 + a3);
            const int chunk = tid / HID;  // 0:i 1:f 2:g 3:o
            float av;
            if (chunk == 2) av = tanhf(acc);
            else av = 1.f / (1.f + expf(-acc));
            gact[tid] = av;
        }
        __syncthreads();
        if (tid < HID) {
            const float iv = gact[tid], fv = gact[HID + tid];
            const float gv = gact[2 * HID + tid], ov = gact[3 * HID + tid];
            c_reg = fv * c_reg + iv * gv;
            const float hv = ov * tanhf(c_reg);
            h_lds[tid] = hv;
            hs0[(size_t)tcur * HID + tid] = hv;
        }
        t += tstep;
        __syncthreads();
    }
}

// ---------------- attention row0/col0 + mean/max vectors ----------------
__global__ __launch_bounds__(128) void attn_kernel(
    const float* __restrict__ hs_ctx, float* __restrict__ av)
{
    const int d = blockIdx.x >> 5;
    const int b = blockIdx.x & 31;
    const float* __restrict__ cp = hs_ctx + ((size_t)(0 + d) * B_ + b) * T_ * HID;
    const float* __restrict__ ch = hs_ctx + ((size_t)(2 + d) * B_ + b) * T_ * HID;
    const int tid = threadIdx.x;
    __shared__ float cp0[HID], ch0[HID];
    __shared__ float arow[T_], acol[T_];
    __shared__ float nrm[2], asum[2];
    if (tid < HID) { cp0[tid] = cp[tid]; ch0[tid] = ch[tid]; }
    __syncthreads();
    if (tid < 2) {
        const float* v = tid ? ch0 : cp0;
        float sum = 0.f;
        for (int h = 0; h < HID; h++) sum += v[h] * v[h];
        nrm[tid] = sqrtf(sum);
    }
    __syncthreads();
    if (tid < T_) {
        const float* r = ch + (size_t)tid * HID;
        float dot = 0.f, n2 = 0.f;
        for (int h = 0; h < HID; h++) { const float x = r[h]; dot += cp0[h] * x; n2 += x * x; }
        arow[tid] = dot / (nrm[0] * sqrtf(n2));
    } else if (tid >= 64 && tid < 64 + T_) {
        const int i = tid - 64;
        const float* r = cp + (size_t)i * HID;
        float dot = 0.f, n2 = 0.f;
        for (int h = 0; h < HID; h++) { const float x = r[h]; dot += x * ch0[h]; n2 += x * x; }
        acol[i] = dot / (sqrtf(n2) * nrm[1]);
    }
    __syncthreads();
    if (tid < 2) {
        const float* a = tid ? acol : arow;
        float sum = 0.f;
        for (int j = 0; j < T_; j++) sum += a[j];
        asum[tid] = sum;
    }
    __syncthreads();
    if (tid < HID) {
        float m = 0.f, mx = -INFINITY;
        for (int j = 0; j < T_; j++) {
            const float x = ch[(size_t)j * HID + tid] * arow[j];
            m += x; mx = fmaxf(mx, x);
        }
        av[((size_t)(d * 4 + 0) * B_ + b) * HID + tid] = m / (asum[0] + 1e-10f);
        av[((size_t)(d * 4 + 1) * B_ + b) * HID + tid] = mx;
        float m2 = 0.f, mx2 = -INFINITY;
        for (int i = 0; i < T_; i++) {
            const float x = cp[(size_t)i * HID + tid] * acol[i];
            m2 += x; mx2 = fmaxf(mx2, x);
        }
        av[((size_t)(d * 4 + 2) * B_ + b) * HID + tid] = m2 / (asum[1] + 1e-10f);
        av[((size_t)(d * 4 + 3) * B_ + b) * HID + tid] = mx2;
    }
}

// ---------------- multi-perspective single (v1 vs broadcast u) ----------------
struct MPCfg {
    const float* v1;
    const float* u;
    int ustride;
    const float* w;
    float* outp;
    int choff;
};
struct MPCfgs { MPCfg c[12]; };

__global__ __launch_bounds__(256) void mp_single_kernel(MPCfgs cfgs)
{
    const int ci = blockIdx.x >> 5;
    const int b = blockIdx.x & 31;
    const MPCfg cfg = cfgs.c[ci];
    const int tid = threadIdx.x;
    __shared__ float w2[HID][L_];
    __shared__ float uw[HID][L_];
    __shared__ float u_l[HID];
    __shared__ float nul[L_];
    if (tid < HID) u_l[tid] = cfg.u[(size_t)b * cfg.ustride + tid];
    for (int e = tid; e < HID * L_; e += 256) {
        const float wv = cfg.w[e];
        w2[e / L_][e % L_] = wv * wv;
    }
    __syncthreads();
    for (int e = tid; e < HID * L_; e += 256) uw[e / L_][e % L_] = w2[e / L_][e % L_] * u_l[e / L_];
    if (tid < L_) {
        float sum = 0.f;
        for (int h = 0; h < HID; h++) sum += u_l[h] * u_l[h] * w2[h][tid];
        nul[tid] = sqrtf(sum);
    }
    __syncthreads();
    const float* __restrict__ v1b = cfg.v1 + (size_t)b * T_ * HID;
    for (int p = tid; p < T_ * L_; p += 256) {
        const int i = p / L_, l = p % L_;
        const float* __restrict__ v = v1b + (size_t)i * HID;
        float num = 0.f, den = 0.f;
        for (int h = 0; h < HID; h++) {
            const float x = v[h];
            num = fmaf(x, uw[h][l], num);
            den = fmaf(x * x, w2[h][l], den);
        }
        cfg.outp[((size_t)b * T_ + i) * 160 + cfg.choff + l] = num / (sqrtf(den) * nul[l]);
    }
}

// ---------------- pairwise multi-perspective max ----------------
__global__ __launch_bounds__(256) void mp_pair_kernel(
    const float* __restrict__ hs_ctx, const float* __restrict__ w3,
    const float* __restrict__ w4, float* __restrict__ mv_p, float* __restrict__ mv_h)
{
    const int x = blockIdx.x;
    const int l = x % L_;
    const int b = (x / L_) & 31;
    const int d = x / (L_ * B_);
    const float* __restrict__ cp = hs_ctx + ((size_t)(0 + d) * B_ + b) * T_ * HID;
    const float* __restrict__ ch = hs_ctx + ((size_t)(2 + d) * B_ + b) * T_ * HID;
    const float* __restrict__ w = d ? w4 : w3;
    const int tid = threadIdx.x;
    __shared__ float U[T_][HID];
    __shared__ float V[T_][HID];
    __shared__ float aw[HID];
    __shared__ float n1[T_], n2[T_];
    __shared__ float pmi[T_][15];
    __shared__ float pmj[15][T_];
    if (tid < HID) aw[tid] = fabsf(w[tid * L_ + l]);
    __syncthreads();
    for (int e = tid; e < T_ * HID; e += 256) {
        const int i = e / HID, h = e % HID;
        U[i][h] = cp[e] * aw[h];
        V[i][h] = ch[e] * aw[h];
    }
    __syncthreads();
    if (tid < T_) {
        float sum = 0.f;
        for (int h = 0; h < HID; h++) { const float v = U[tid][h]; sum += v * v; }
        n1[tid] = sqrtf(sum);
    } else if (tid >= 128 && tid < 128 + T_) {
        const int j = tid - 128;
        float sum = 0.f;
        for (int h = 0; h < HID; h++) { const float v = V[j][h]; sum += v * v; }
        n2[j] = sqrtf(sum);
    }
    __syncthreads();
    if (tid < 225) {
        const int ti = tid / 15, tj = tid % 15;
        const int i0 = ti * 4, j0 = tj * 4;
        float acc[4][4] = {};
        for (int h = 0; h < HID; ++h) {
            float uu[4], vv[4];
            #pragma unroll
            for (int r = 0; r < 4; r++) uu[r] = U[i0 + r][h];
            #pragma unroll
            for (int s2 = 0; s2 < 4; s2++) vv[s2] = V[j0 + s2][h];
            #pragma unroll
            for (int r = 0; r < 4; r++)
                #pragma unroll
                for (int s2 = 0; s2 < 4; s2++) acc[r][s2] = fmaf(uu[r], vv[s2], acc[r][s2]);
        }
        float rmax[4] = {-INFINITY, -INFINITY, -INFINITY, -INFINITY};
        float cmax[4] = {-INFINITY, -INFINITY, -INFINITY, -INFINITY};
        #pragma unroll
        for (int r = 0; r < 4; r++)
            #pragma unroll
            for (int s2 = 0; s2 < 4; s2++) {
                const float val = acc[r][s2] / (n1[i0 + r] * n2[j0 + s2]);
                rmax[r] = fmaxf(rmax[r], val);
                cmax[s2] = fmaxf(cmax[s2], val);
            }
        #pragma unroll
        for (int r = 0; r < 4; r++) pmi[i0 + r][tj] = rmax[r];
        #pragma unroll
        for (int s2 = 0; s2 < 4; s2++) pmj[ti][j0 + s2] = cmax[s2];
    }
    __syncthreads();
    if (tid < T_) {
        float mx = -INFINITY;
        for (int q = 0; q < 15; q++) mx = fmaxf(mx, pmi[tid][q]);
        mv_p[((size_t)b * T_ + tid) * 160 + d * 80 + 20 + l] = mx;
    } else if (tid >= 128 && tid < 128 + T_) {
        const int j = tid - 128;
        float mx = -INFINITY;
        for (int q = 0; q < 15; q++) mx = fmaxf(mx, pmj[q][j]);
        mv_h[((size_t)b * T_ + j) * 160 + d * 80 + 20 + l] = mx;
    }
}

// ---------------- final FC ----------------
__global__ __launch_bounds__(256) void fc_final(
    const float* __restrict__ hs_agg, const float* __restrict__ fc1W,
    const float* __restrict__ fc1b, const float* __restrict__ fc2W,
    const float* __restrict__ fc2b, float* __restrict__ out)
{
    const int b = blockIdx.x;
    const int tid = threadIdx.x;
    __shared__ float x[400];
    __shared__ float y[200];
    if (tid < HID) {
        x[tid]           = hs_agg[((size_t)(0 * B_ + b) * T_ + 59) * HID + tid];
        x[HID + tid]     = hs_agg[((size_t)(1 * B_ + b) * T_ + 0) * HID + tid];
        x[2 * HID + tid] = hs_agg[((size_t)(2 * B_ + b) * T_ + 59) * HID + tid];
        x[3 * HID + tid] = hs_agg[((size_t)(3 * B_ + b) * T_ + 0) * HID + tid];
    }
    __syncthreads();
    if (tid < 200) {
        float s = fc1b[tid];
        const float* __restrict__ wr = fc1W + (size_t)tid * 400;
        for (int k = 0; k < 400; k++) s = fmaf(x[k], wr[k], s);
        y[tid] = tanhf(s);
    }
    __syncthreads();
    if (tid < 3) {
        float s = fc2b[tid];
        const float* __restrict__ wr = fc2W + (size_t)tid * 200;
        for (int k = 0; k < 200; k++) s = fmaf(y[k], wr[k], s);
        out[b * 3 + tid] = s;
    }
}

extern "C" void kernel_launch(void* const* d_in, const int* in_sizes, int n_in,
                              void* d_out, int out_size, void* d_ws, size_t ws_size,
                              hipStream_t stream) {
    const int* p_idx = (const int*)d_in[0];
    const int* h_idx = (const int*)d_in[1];
    const float* emb = (const float*)d_in[2];
    const float* ctx_Wih_f = (const float*)d_in[3];
    const float* ctx_Whh_f = (const float*)d_in[4];
    const float* ctx_bih_f = (const float*)d_in[5];
    const float* ctx_bhh_f = (const float*)d_in[6];
    const float* ctx_Wih_b = (const float*)d_in[7];
    const float* ctx_Whh_b = (const float*)d_in[8];
    const float* ctx_bih_b = (const float*)d_in[9];
    const float* ctx_bhh_b = (const float*)d_in[10];
    const float* agg_Wih_f = (const float*)d_in[11];
    const float* agg_Whh_f = (const float*)d_in[12];
    const float* agg_bih_f = (const float*)d_in[13];
    const float* agg_bhh_f = (const float*)d_in[14];
    const float* agg_Wih_b = (const float*)d_in[15];
    const float* agg_Whh_b = (const float*)d_in[16];
    const float* agg_bih_b = (const float*)d_in[17];
    const float* agg_bhh_b = (const float*)d_in[18];
    const float* w1 = (const float*)d_in[19];
    const float* w2 = (const float*)d_in[20];
    const float* w3 = (const float*)d_in[21];
    const float* w4 = (const float*)d_in[22];
    const float* w5 = (const float*)d_in[23];
    const float* w6 = (const float*)d_in[24];
    const float* w7 = (const float*)d_in[25];
    const float* w8 = (const float*)d_in[26];
    const float* fc1W = (const float*)d_in[27];
    const float* fc1b = (const float*)d_in[28];
    const float* fc2W = (const float*)d_in[29];
    const float* fc2b = (const float*)d_in[30];

    float* ws = (float*)d_ws;
    float* xp = ws + XP_OFF;
    float* hsc = ws + HSC_OFF;
    float* hsa = ws + HSA_OFF;
    float* mvp = ws + MV_OFF;
    float* mvh = mvp + (size_t)B_ * T_ * 160;
    float* av = ws + AV_OFF;

    const dim3 ggrid(13, 60);  // N=800 -> 13 tiles of 64, M=3840 -> 60

    // ctx input GEMMs (emb gather fused), K=300
    gemm_dual<<<ggrid, 256, 0, stream>>>(emb, emb, p_idx, h_idx,
                                         ctx_Wih_f, ctx_Wih_b, ctx_bih_f, ctx_bih_b, xp, 300);

    lstm_scan<<<128, 512, 0, stream>>>(xp, ctx_Whh_f, ctx_Whh_b, ctx_bhh_f, ctx_bhh_b, hsc);

    attn_kernel<<<64, 128, 0, stream>>>(hsc, av);

    MPCfgs cfgs;
    for (int d = 0; d < 2; d++) {
        const float* cp_d = hsc + (size_t)(0 + d) * B_ * T_ * HID;
        const float* ch_d = hsc + (size_t)(2 + d) * B_ * T_ * HID;
        const int last = d ? 0 : (T_ - 1);
        const float* wfull = d ? w2 : w1;
        const float* wam = d ? w6 : w5;
        const float* wamax = d ? w8 : w7;
        float* avp0 = av + (size_t)(d * 4 + 0) * B_ * HID;
        float* avp1 = av + (size_t)(d * 4 + 1) * B_ * HID;
        float* avp2 = av + (size_t)(d * 4 + 2) * B_ * HID;
        float* avp3 = av + (size_t)(d * 4 + 3) * B_ * HID;
        cfgs.c[d * 6 + 0] = {cp_d, ch_d + last * HID, T_ * HID, wfull, mvp, d * 80 + 0};
        cfgs.c[d * 6 + 1] = {cp_d, avp0, HID, wam, mvp, d * 80 + 40};
        cfgs.c[d * 6 + 2] = {cp_d, avp1, HID, wamax, mvp, d * 80 + 60};
        cfgs.c[d * 6 + 3] = {ch_d, cp_d + last * HID, T_ * HID, wfull, mvh, d * 80 + 0};
        cfgs.c[d * 6 + 4] = {ch_d, avp2, HID, wam, mvh, d * 80 + 40};
        cfgs.c[d * 6 + 5] = {ch_d, avp3, HID, wamax, mvh, d * 80 + 60};
    }
    mp_single_kernel<<<384, 256, 0, stream>>>(cfgs);
    mp_pair_kernel<<<1280, 256, 0, stream>>>(hsc, w3, w4, mvp, mvh);

    // agg input GEMMs, K=160
    gemm_dual<<<ggrid, 256, 0, stream>>>(mvp, mvh, nullptr, nullptr,
                                         agg_Wih_f, agg_Wih_b, agg_bih_f, agg_bih_b, xp, 160);

    lstm_scan<<<128, 512, 0, stream>>>(xp, agg_Whh_f, agg_Whh_b, agg_bhh_f, agg_bhh_b, hsa);

    fc_final<<<32, 256, 0, stream>>>(hsa, fc1W, fc1b, fc2W, fc2b, (float*)d_out);
}

// Round 4
// 360.584 us; speedup vs baseline: 2.5049x; 1.1402x over previous
//
#include <hip/hip_runtime.h>
#include <math.h>

#define B_   32
#define T_   60
#define D_   300
#define HID  100
#define G4   400   // 4*HID gates
#define L_   20

// ---- workspace layout (in floats) ----
#define XP_OFF   0u
#define HSC_OFF  3072000u
#define HSA_OFF  3840000u
#define MV_OFF   4608000u
#define AV_OFF   5222400u

// ---------------- fused dual GEMM with optional row-gather + bias ----------------
// Computes C[s][m][n] for s = 2*(src==A1) + (weights==Wb);
// M = 2*1920 rows (A0 rows then A1 rows), N = 2*400 cols (Wf then Wb), layout [4][1920][400].
__global__ __launch_bounds__(256) void gemm_dual(
    const float* __restrict__ A0, const float* __restrict__ A1,
    const int* __restrict__ idx0, const int* __restrict__ idx1,
    const float* __restrict__ Wf, const float* __restrict__ Wb,
    const float* __restrict__ bf, const float* __restrict__ bb,
    float* __restrict__ C, int K)
{
    __shared__ float As[16][68];
    __shared__ float Bs[16][68];
    const int tid = threadIdx.x;
    const int m0 = blockIdx.y * 64;   // 0..3776
    const int n0 = blockIdx.x * 64;   // 0..768
    const bool is_h = (m0 >= 1920);
    const float* __restrict__ Abase = is_h ? A1 : A0;
    const int* __restrict__ idx = is_h ? idx1 : idx0;
    const int mloc0 = m0 - (is_h ? 1920 : 0);

    const int r = tid >> 2;        // 0..63
    const int q = tid & 3;         // 0..3

    const int arow = mloc0 + r;
    const int srow = idx ? idx[arow] : arow;
    const float* __restrict__ Arow = Abase + (size_t)srow * K;
    const int n_my = n0 + r;
    const float* __restrict__ Wrow = (n_my < 400) ? (Wf + (size_t)n_my * K)
                      : ((n_my < 800) ? (Wb + (size_t)(n_my - 400) * K) : nullptr);

    const int tm = (tid >> 4) << 2;
    const int tn = (tid & 15) << 2;
    float acc[4][4] = {};
    for (int k0 = 0; k0 < K; k0 += 16) {
        const int k = k0 + q * 4;
        float4 av4 = make_float4(0.f, 0.f, 0.f, 0.f);
        float4 bv4 = make_float4(0.f, 0.f, 0.f, 0.f);
        if (k < K) av4 = *reinterpret_cast<const float4*>(Arow + k);
        if (Wrow != nullptr && k < K) bv4 = *reinterpret_cast<const float4*>(Wrow + k);
        __syncthreads();
        As[q * 4 + 0][r] = av4.x; As[q * 4 + 1][r] = av4.y;
        As[q * 4 + 2][r] = av4.z; As[q * 4 + 3][r] = av4.w;
        Bs[q * 4 + 0][r] = bv4.x; Bs[q * 4 + 1][r] = bv4.y;
        Bs[q * 4 + 2][r] = bv4.z; Bs[q * 4 + 3][r] = bv4.w;
        __syncthreads();
        #pragma unroll
        for (int kk = 0; kk < 16; ++kk) {
            const float4 a4 = *reinterpret_cast<const float4*>(&As[kk][tm]);
            const float4 b4 = *reinterpret_cast<const float4*>(&Bs[kk][tn]);
            const float a[4] = {a4.x, a4.y, a4.z, a4.w};
            const float b[4] = {b4.x, b4.y, b4.z, b4.w};
            #pragma unroll
            for (int i = 0; i < 4; i++)
                #pragma unroll
                for (int j = 0; j < 4; j++) acc[i][j] = fmaf(a[i], b[j], acc[i][j]);
        }
    }
    #pragma unroll
    for (int i = 0; i < 4; i++)
        #pragma unroll
        for (int j = 0; j < 4; j++) {
            const int n = n0 + tn + j;
            if (n < 800) {
                const int m = m0 + tm + i;
                const int s = (m >= 1920 ? 2 : 0) + (n >= 400 ? 1 : 0);
                const int ml = m - (m >= 1920 ? 1920 : 0);
                const int nl = n - (n >= 400 ? 400 : 0);
                const float bias = (n >= 400) ? bb[nl] : bf[nl];
                C[((size_t)s * 1920 + ml) * 400 + nl] = acc[i][j] + bias;
            }
        }
}

// ---------------- LSTM scan: 1 (scan,batch) per block, 128 blocks ----------------
__global__ __launch_bounds__(512, 1) void lstm_scan(
    const float* __restrict__ xp,
    const float* __restrict__ Whh_f, const float* __restrict__ Whh_b,
    const float* __restrict__ bhh_f, const float* __restrict__ bhh_b,
    float* __restrict__ hs)
{
    const int blk = blockIdx.x;
    const int s = blk >> 5, b = blk & 31;
    const int dir = s & 1;
    const float* __restrict__ Whh = dir ? Whh_b : Whh_f;
    const float* __restrict__ bhh = dir ? bhh_b : bhh_f;
    const int tid = threadIdx.x;

    __shared__ __align__(16) float h_lds[HID];
    __shared__ float gact[G4];

    float wreg[HID];
    float bias = 0.f;
    if (tid < G4) {
        bias = bhh[tid];
        #pragma unroll
        for (int k = 0; k < HID; ++k) wreg[k] = Whh[tid * HID + k];
    }
    if (tid < HID) h_lds[tid] = 0.f;
    float c_reg = 0.f;

    const float* __restrict__ xp0 = xp + ((size_t)s * B_ + b) * T_ * G4;
    float* __restrict__ hs0 = hs + ((size_t)s * B_ + b) * T_ * HID;

    int t = dir ? (T_ - 1) : 0;
    const int tstep = dir ? -1 : 1;
    float xr = (tid < G4) ? xp0[(size_t)t * G4 + tid] : 0.f;
    __syncthreads();

    for (int st = 0; st < T_; ++st) {
        const int tcur = t;
        if (tid < G4) {
            float a0 = bias + xr, a1 = 0.f, a2 = 0.f, a3 = 0.f;
            #pragma unroll
            for (int k = 0; k < HID; k += 4) {
                const float4 h4 = *reinterpret_cast<const float4*>(&h_lds[k]);
                a0 = fmaf(h4.x, wreg[k + 0], a0);
                a1 = fmaf(h4.y, wreg[k + 1], a1);
                a2 = fmaf(h4.z, wreg[k + 2], a2);
                a3 = fmaf(h4.w, wreg[k + 3], a3);
            }
            if (st + 1 < T_) xr = xp0[(size_t)(t + tstep) * G4 + tid];
            const float acc = (a0 + a1) + (a2 + a3);
            const int chunk = tid / HID;  // 0:i 1:f 2:g 3:o
            float av;
            if (chunk == 2) av = tanhf(acc);
            else av = 1.f / (1.f + expf(-acc));
            gact[tid] = av;
        }
        __syncthreads();
        if (tid < HID) {
            const float iv = gact[tid], fv = gact[HID + tid];
            const float gv = gact[2 * HID + tid], ov = gact[3 * HID + tid];
            c_reg = fv * c_reg + iv * gv;
            const float hv = ov * tanhf(c_reg);
            h_lds[tid] = hv;
            hs0[(size_t)tcur * HID + tid] = hv;
        }
        t += tstep;
        __syncthreads();
    }
}

// ---------------- attention row0/col0 + mean/max vectors ----------------
__global__ __launch_bounds__(128) void attn_kernel(
    const float* __restrict__ hs_ctx, float* __restrict__ av)
{
    const int d = blockIdx.x >> 5;
    const int b = blockIdx.x & 31;
    const float* __restrict__ cp = hs_ctx + ((size_t)(0 + d) * B_ + b) * T_ * HID;
    const float* __restrict__ ch = hs_ctx + ((size_t)(2 + d) * B_ + b) * T_ * HID;
    const int tid = threadIdx.x;
    __shared__ float cp0[HID], ch0[HID];
    __shared__ float arow[T_], acol[T_];
    __shared__ float nrm[2], asum[2];
    if (tid < HID) { cp0[tid] = cp[tid]; ch0[tid] = ch[tid]; }
    __syncthreads();
    if (tid < 2) {
        const float* v = tid ? ch0 : cp0;
        float sum = 0.f;
        for (int h = 0; h < HID; h++) sum += v[h] * v[h];
        nrm[tid] = sqrtf(sum);
    }
    __syncthreads();
    if (tid < T_) {
        const float* r = ch + (size_t)tid * HID;
        float dot = 0.f, n2 = 0.f;
        for (int h = 0; h < HID; h++) { const float x = r[h]; dot += cp0[h] * x; n2 += x * x; }
        arow[tid] = dot / (nrm[0] * sqrtf(n2));
    } else if (tid >= 64 && tid < 64 + T_) {
        const int i = tid - 64;
        const float* r = cp + (size_t)i * HID;
        float dot = 0.f, n2 = 0.f;
        for (int h = 0; h < HID; h++) { const float x = r[h]; dot += x * ch0[h]; n2 += x * x; }
        acol[i] = dot / (sqrtf(n2) * nrm[1]);
    }
    __syncthreads();
    if (tid < 2) {
        const float* a = tid ? acol : arow;
        float sum = 0.f;
        for (int j = 0; j < T_; j++) sum += a[j];
        asum[tid] = sum;
    }
    __syncthreads();
    if (tid < HID) {
        float m = 0.f, mx = -INFINITY;
        for (int j = 0; j < T_; j++) {
            const float x = ch[(size_t)j * HID + tid] * arow[j];
            m += x; mx = fmaxf(mx, x);
        }
        av[((size_t)(d * 4 + 0) * B_ + b) * HID + tid] = m / (asum[0] + 1e-10f);
        av[((size_t)(d * 4 + 1) * B_ + b) * HID + tid] = mx;
        float m2 = 0.f, mx2 = -INFINITY;
        for (int i = 0; i < T_; i++) {
            const float x = cp[(size_t)i * HID + tid] * acol[i];
            m2 += x; mx2 = fmaxf(mx2, x);
        }
        av[((size_t)(d * 4 + 2) * B_ + b) * HID + tid] = m2 / (asum[1] + 1e-10f);
        av[((size_t)(d * 4 + 3) * B_ + b) * HID + tid] = mx2;
    }
}

// ---------------- multi-perspective single (v1 vs broadcast u) ----------------
struct MPCfg {
    const float* v1;
    const float* u;
    int ustride;
    const float* w;
    float* outp;
    int choff;
};
struct MPCfgs { MPCfg c[12]; };

__global__ __launch_bounds__(256) void mp_single_kernel(MPCfgs cfgs)
{
    const int ci = blockIdx.x >> 5;
    const int b = blockIdx.x & 31;
    const MPCfg cfg = cfgs.c[ci];
    const int tid = threadIdx.x;
    __shared__ float w2[HID][L_];
    __shared__ float uw[HID][L_];
    __shared__ float u_l[HID];
    __shared__ float nul[L_];
    if (tid < HID) u_l[tid] = cfg.u[(size_t)b * cfg.ustride + tid];
    for (int e = tid; e < HID * L_; e += 256) {
        const float wv = cfg.w[e];
        w2[e / L_][e % L_] = wv * wv;
    }
    __syncthreads();
    for (int e = tid; e < HID * L_; e += 256) uw[e / L_][e % L_] = w2[e / L_][e % L_] * u_l[e / L_];
    if (tid < L_) {
        float sum = 0.f;
        for (int h = 0; h < HID; h++) sum += u_l[h] * u_l[h] * w2[h][tid];
        nul[tid] = sqrtf(sum);
    }
    __syncthreads();
    const float* __restrict__ v1b = cfg.v1 + (size_t)b * T_ * HID;
    for (int p = tid; p < T_ * L_; p += 256) {
        const int i = p / L_, l = p % L_;
        const float* __restrict__ v = v1b + (size_t)i * HID;
        float num = 0.f, den = 0.f;
        for (int h = 0; h < HID; h++) {
            const float x = v[h];
            num = fmaf(x, uw[h][l], num);
            den = fmaf(x * x, w2[h][l], den);
        }
        cfg.outp[((size_t)b * T_ + i) * 160 + cfg.choff + l] = num / (sqrtf(den) * nul[l]);
    }
}

// ---------------- pairwise multi-perspective max (v2: transposed LDS + b128) ----------------
// grid: d(2) x b(32) x l(20); per block: U_t[h][i] = cp[i][h]*|w_l[h]|, V_t similarly.
// Inner loop: 2x ds_read_b128 + 16 FMA per h. Partial-max arrays overlay Ut after loop.
__global__ __launch_bounds__(256) void mp_pair_kernel(
    const float* __restrict__ hs_ctx, const float* __restrict__ w3,
    const float* __restrict__ w4, float* __restrict__ mv_p, float* __restrict__ mv_h)
{
    const int x = blockIdx.x;
    const int l = x % L_;
    const int b = (x / L_) & 31;
    const int d = x / (L_ * B_);
    const float* __restrict__ cp = hs_ctx + ((size_t)(0 + d) * B_ + b) * T_ * HID;
    const float* __restrict__ ch = hs_ctx + ((size_t)(2 + d) * B_ + b) * T_ * HID;
    const float* __restrict__ w = d ? w4 : w3;
    const int tid = threadIdx.x;

    __shared__ __align__(16) float Ut[HID][T_];   // 24 KB, transposed & scaled
    __shared__ __align__(16) float Vt[HID][T_];   // 24 KB
    __shared__ float aw[HID];
    __shared__ float rn1[T_], rn2[T_];
    // partial-max arrays overlaid onto Ut after the main loop (saves 7.7 KB -> 3 blocks/CU)
    float* pmi = &Ut[0][0];                 // [60][17]
    float* pmj = &Ut[0][0] + 60 * 17 + 4;   // [15][61]

    if (tid < HID) aw[tid] = fabsf(w[tid * L_ + l]);
    __syncthreads();
    // coalesced global read, transposed LDS write (8-way write conflict, one-time)
    for (int e = tid; e < T_ * HID; e += 256) {
        const int i = e / HID, h = e % HID;
        const float a = aw[h];
        Ut[h][i] = cp[e] * a;
        Vt[h][i] = ch[e] * a;
    }
    __syncthreads();
    // reciprocal norms; column reads are stride-1 across lanes (conflict-free)
    if (tid < T_) {
        float s = 0.f;
        for (int h = 0; h < HID; h++) { const float v = Ut[h][tid]; s = fmaf(v, v, s); }
        rn1[tid] = 1.0f / sqrtf(s);
    } else if (tid >= 64 && tid < 64 + T_) {
        const int j = tid - 64;
        float s = 0.f;
        for (int h = 0; h < HID; h++) { const float v = Vt[h][j]; s = fmaf(v, v, s); }
        rn2[j] = 1.0f / sqrtf(s);
    }
    __syncthreads();

    float rmax[4], cmax[4];
    int i0 = 0, j0 = 0, ti = 0, tj = 0;
    if (tid < 225) {
        tj = tid % 15;   // i-tile
        ti = tid / 15;   // j-tile
        i0 = tj * 4; j0 = ti * 4;
        float acc[4][4] = {};
        #pragma unroll 4
        for (int h = 0; h < HID; ++h) {
            const float4 u = *reinterpret_cast<const float4*>(&Ut[h][i0]);
            const float4 v = *reinterpret_cast<const float4*>(&Vt[h][j0]);
            const float uu[4] = {u.x, u.y, u.z, u.w};
            const float vv[4] = {v.x, v.y, v.z, v.w};
            #pragma unroll
            for (int r2 = 0; r2 < 4; r2++)
                #pragma unroll
                for (int s2 = 0; s2 < 4; s2++) acc[r2][s2] = fmaf(uu[r2], vv[s2], acc[r2][s2]);
        }
        const float r1[4] = {rn1[i0], rn1[i0 + 1], rn1[i0 + 2], rn1[i0 + 3]};
        const float r2v[4] = {rn2[j0], rn2[j0 + 1], rn2[j0 + 2], rn2[j0 + 3]};
        #pragma unroll
        for (int r2 = 0; r2 < 4; r2++) { rmax[r2] = -INFINITY; }
        #pragma unroll
        for (int s2 = 0; s2 < 4; s2++) { cmax[s2] = -INFINITY; }
        #pragma unroll
        for (int r2 = 0; r2 < 4; r2++)
            #pragma unroll
            for (int s2 = 0; s2 < 4; s2++) {
                const float val = acc[r2][s2] * (r1[r2] * r2v[s2]);
                rmax[r2] = fmaxf(rmax[r2], val);
                cmax[s2] = fmaxf(cmax[s2], val);
            }
    }
    __syncthreads();   // all Ut reads done before overlay
    if (tid < 225) {
        #pragma unroll
        for (int r2 = 0; r2 < 4; r2++) pmi[(i0 + r2) * 17 + ti] = rmax[r2];
        #pragma unroll
        for (int s2 = 0; s2 < 4; s2++) pmj[tj * 61 + (j0 + s2)] = cmax[s2];
    }
    __syncthreads();
    if (tid < T_) {
        float mx = -INFINITY;
        for (int q = 0; q < 15; q++) mx = fmaxf(mx, pmi[tid * 17 + q]);
        mv_p[((size_t)b * T_ + tid) * 160 + d * 80 + 20 + l] = mx;
    } else if (tid >= 64 && tid < 64 + T_) {
        const int j = tid - 64;
        float mx = -INFINITY;
        for (int q = 0; q < 15; q++) mx = fmaxf(mx, pmj[q * 61 + j]);
        mv_h[((size_t)b * T_ + j) * 160 + d * 80 + 20 + l] = mx;
    }
}

// ---------------- final FC ----------------
__global__ __launch_bounds__(256) void fc_final(
    const float* __restrict__ hs_agg, const float* __restrict__ fc1W,
    const float* __restrict__ fc1b, const float* __restrict__ fc2W,
    const float* __restrict__ fc2b, float* __restrict__ out)
{
    const int b = blockIdx.x;
    const int tid = threadIdx.x;
    __shared__ float x[400];
    __shared__ float y[200];
    if (tid < HID) {
        x[tid]           = hs_agg[((size_t)(0 * B_ + b) * T_ + 59) * HID + tid];
        x[HID + tid]     = hs_agg[((size_t)(1 * B_ + b) * T_ + 0) * HID + tid];
        x[2 * HID + tid] = hs_agg[((size_t)(2 * B_ + b) * T_ + 59) * HID + tid];
        x[3 * HID + tid] = hs_agg[((size_t)(3 * B_ + b) * T_ + 0) * HID + tid];
    }
    __syncthreads();
    if (tid < 200) {
        float s = fc1b[tid];
        const float* __restrict__ wr = fc1W + (size_t)tid * 400;
        for (int k = 0; k < 400; k++) s = fmaf(x[k], wr[k], s);
        y[tid] = tanhf(s);
    }
    __syncthreads();
    if (tid < 3) {
        float s = fc2b[tid];
        const float* __restrict__ wr = fc2W + (size_t)tid * 200;
        for (int k = 0; k < 200; k++) s = fmaf(y[k], wr[k], s);
        out[b * 3 + tid] = s;
    }
}

extern "C" void kernel_launch(void* const* d_in, const int* in_sizes, int n_in,
                              void* d_out, int out_size, void* d_ws, size_t ws_size,
                              hipStream_t stream) {
    const int* p_idx = (const int*)d_in[0];
    const int* h_idx = (const int*)d_in[1];
    const float* emb = (const float*)d_in[2];
    const float* ctx_Wih_f = (const float*)d_in[3];
    const float* ctx_Whh_f = (const float*)d_in[4];
    const float* ctx_bih_f = (const float*)d_in[5];
    const float* ctx_bhh_f = (const float*)d_in[6];
    const float* ctx_Wih_b = (const float*)d_in[7];
    const float* ctx_Whh_b = (const float*)d_in[8];
    const float* ctx_bih_b = (const float*)d_in[9];
    const float* ctx_bhh_b = (const float*)d_in[10];
    const float* agg_Wih_f = (const float*)d_in[11];
    const float* agg_Whh_f = (const float*)d_in[12];
    const float* agg_bih_f = (const float*)d_in[13];
    const float* agg_bhh_f = (const float*)d_in[14];
    const float* agg_Wih_b = (const float*)d_in[15];
    const float* agg_Whh_b = (const float*)d_in[16];
    const float* agg_bih_b = (const float*)d_in[17];
    const float* agg_bhh_b = (const float*)d_in[18];
    const float* w1 = (const float*)d_in[19];
    const float* w2 = (const float*)d_in[20];
    const float* w3 = (const float*)d_in[21];
    const float* w4 = (const float*)d_in[22];
    const float* w5 = (const float*)d_in[23];
    const float* w6 = (const float*)d_in[24];
    const float* w7 = (const float*)d_in[25];
    const float* w8 = (const float*)d_in[26];
    const float* fc1W = (const float*)d_in[27];
    const float* fc1b = (const float*)d_in[28];
    const float* fc2W = (const float*)d_in[29];
    const float* fc2b = (const float*)d_in[30];

    float* ws = (float*)d_ws;
    float* xp = ws + XP_OFF;
    float* hsc = ws + HSC_OFF;
    float* hsa = ws + HSA_OFF;
    float* mvp = ws + MV_OFF;
    float* mvh = mvp + (size_t)B_ * T_ * 160;
    float* av = ws + AV_OFF;

    const dim3 ggrid(13, 60);  // N=800 -> 13 tiles of 64, M=3840 -> 60

    // ctx input GEMMs (emb gather fused), K=300
    gemm_dual<<<ggrid, 256, 0, stream>>>(emb, emb, p_idx, h_idx,
                                         ctx_Wih_f, ctx_Wih_b, ctx_bih_f, ctx_bih_b, xp, 300);

    lstm_scan<<<128, 512, 0, stream>>>(xp, ctx_Whh_f, ctx_Whh_b, ctx_bhh_f, ctx_bhh_b, hsc);

    attn_kernel<<<64, 128, 0, stream>>>(hsc, av);

    MPCfgs cfgs;
    for (int d = 0; d < 2; d++) {
        const float* cp_d = hsc + (size_t)(0 + d) * B_ * T_ * HID;
        const float* ch_d = hsc + (size_t)(2 + d) * B_ * T_ * HID;
        const int last = d ? 0 : (T_ - 1);
        const float* wfull = d ? w2 : w1;
        const float* wam = d ? w6 : w5;
        const float* wamax = d ? w8 : w7;
        float* avp0 = av + (size_t)(d * 4 + 0) * B_ * HID;
        float* avp1 = av + (size_t)(d * 4 + 1) * B_ * HID;
        float* avp2 = av + (size_t)(d * 4 + 2) * B_ * HID;
        float* avp3 = av + (size_t)(d * 4 + 3) * B_ * HID;
        cfgs.c[d * 6 + 0] = {cp_d, ch_d + last * HID, T_ * HID, wfull, mvp, d * 80 + 0};
        cfgs.c[d * 6 + 1] = {cp_d, avp0, HID, wam, mvp, d * 80 + 40};
        cfgs.c[d * 6 + 2] = {cp_d, avp1, HID, wamax, mvp, d * 80 + 60};
        cfgs.c[d * 6 + 3] = {ch_d, cp_d + last * HID, T_ * HID, wfull, mvh, d * 80 + 0};
        cfgs.c[d * 6 + 4] = {ch_d, avp2, HID, wam, mvh, d * 80 + 40};
        cfgs.c[d * 6 + 5] = {ch_d, avp3, HID, wamax, mvh, d * 80 + 60};
    }
    mp_single_kernel<<<384, 256, 0, stream>>>(cfgs);
    mp_pair_kernel<<<1280, 256, 0, stream>>>(hsc, w3, w4, mvp, mvh);

    // agg input GEMMs, K=160
    gemm_dual<<<ggrid, 256, 0, stream>>>(mvp, mvh, nullptr, nullptr,
                                         agg_Wih_f, agg_Wih_b, agg_bih_f, agg_bih_b, xp, 160);

    lstm_scan<<<128, 512, 0, stream>>>(xp, agg_Whh_f, agg_Whh_b, agg_bhh_f, agg_bhh_b, hsa);

    fc_final<<<32, 256, 0, stream>>>(hsa, fc1W, fc1b, fc2W, fc2b, (float*)d_out);
}